// Round 8
// baseline (282.318 us; speedup 1.0000x reference)
//
#include <hip/hip_runtime.h>
#include <hip/hip_bf16.h>

// Problem constants (fixed by reference)
#define B_ 4
#define S_ 2048
#define D_ 1024
#define H_ 16
#define DK_ 64

typedef __attribute__((ext_vector_type(8))) short short8;
typedef __attribute__((ext_vector_type(4))) float floatx4;
typedef __attribute__((ext_vector_type(16))) float floatx16;
typedef __attribute__((ext_vector_type(4))) unsigned int uint4v;

#define QSCL 0.1803368801111204f  // log2(e)/sqrt(DK): folded into Q in GEMM epilogue

// round-to-nearest-even f32 -> bf16 bits
static __device__ __forceinline__ unsigned short f2bf(float f) {
    unsigned int u = __float_as_uint(f);
    u += 0x7fffu + ((u >> 16) & 1u);
    return (unsigned short)(u >> 16);
}

// pack two f32 -> bf16x2, round-nearest-ties-up via v_perm_b32 (3 VALU ops) [proven]
static __device__ __forceinline__ unsigned int pack2bf_perm(float a, float b) {
    unsigned int u0 = __float_as_uint(a) + 0x8000u;
    unsigned int u1 = __float_as_uint(b) + 0x8000u;
    return __builtin_amdgcn_perm(u1, u0, 0x07060302u);
}

// pack two f32 -> bf16x2 (RNE, for outputs) [proven]
static __device__ __forceinline__ unsigned int pack2bf(float a, float b) {
    return (unsigned int)f2bf(a) | ((unsigned int)f2bf(b) << 16);
}

// v_permlane32_swap_b32 a, b : lanes[32:63] of a  <->  lanes[0:31] of b
#define PLSWAP(a, b) asm volatile("v_permlane32_swap_b32 %0, %1" : "+v"(a), "+v"(b))

// ---------------- fused cast kernel (x + 4 weights in one launch) ----------------
struct CastAll {
    const float* x;
    const float* w[4];
    unsigned short* xd;
    unsigned short* wd[4];
};

__global__ void cast_all_kernel(CastAll a) {
    int i = blockIdx.x * blockDim.x + threadIdx.x; // over float4 groups
    const float* s;
    unsigned short* d;
    int j;
    if (i < 2097152) { // x: 8M elems = 2M float4
        s = a.x; d = a.xd; j = i;
    } else {           // 4 weights: 256K float4 each
        int k = i - 2097152;
        int w = k >> 18;
        j = k & 262143;
        s = a.w[w]; d = a.wd[w];
    }
    float4 v = ((const float4*)s)[j];
    ushort4 o;
    o.x = f2bf(v.x); o.y = f2bf(v.y); o.z = f2bf(v.z); o.w = f2bf(v.w);
    ((ushort4*)d)[j] = o;
}

// ---------------- GEMM (v10, proven best: 128x128, 2-barrier, multi-block/CU) ----------------
// C[m,n] = sum_k A[m,k] * W[n,k]. A: [M,K] bf16; W: [N,K] bf16 (torch [out,in]).
// 128x128 tile, BK=64, 256 threads, global_load_lds width=16.
// LDS swizzle: chunk c (16B) of row r stored at slot c ^ (r&7); staging lane ln
// loads global chunk (ln&7)^(lr) -> coalesced; frag reads conflict-free.
// Grid (m-tile, n-tile, z): id%8 = m-tile%8 -> XCD L2 locality on A.
// VT2 (QKV launch): z==0 (Q) epilogue pre-scales by QSCL; z==2 (V) stores
// transposed Vt[(b*1024+col)][s].
template <typename OutT, bool VT2>
__global__ __launch_bounds__(256) void gemm_bt(
    const unsigned short* __restrict__ A,
    const unsigned short* __restrict__ W0,
    const unsigned short* __restrict__ W1,
    const unsigned short* __restrict__ W2,
    OutT* __restrict__ C0, OutT* __restrict__ C1, OutT* __restrict__ C2,
    int M, int N, int K)
{
    __shared__ __align__(16) unsigned short At[128 * 64]; // [row][slot^swizzle], NO pad
    __shared__ __align__(16) unsigned short Bt[128 * 64];

    const unsigned short* W = (blockIdx.z == 0) ? W0 : ((blockIdx.z == 1) ? W1 : W2);
    OutT* C = (blockIdx.z == 0) ? C0 : ((blockIdx.z == 1) ? C1 : C2);

    const int m0 = blockIdx.x * 128;  // m-tile fastest: id%8 = m-tile%8 -> XCD locality
    const int n0 = blockIdx.y * 128;
    const int wv = threadIdx.x >> 6;
    const int ln = threadIdx.x & 63;
    const int l31 = ln & 31;
    const int half = ln >> 5;
    const int wm = (wv >> 1) * 64; // wave's 64x64 quadrant
    const int wn = (wv & 1) * 64;

    floatx16 acc[2][2]; // [mt][nt] 32x32 tiles
#pragma unroll
    for (int mt = 0; mt < 2; mt++)
#pragma unroll
        for (int nt = 0; nt < 2; nt++)
#pragma unroll
            for (int e = 0; e < 16; e++) acc[mt][nt][e] = 0.f;

    const int lr = ln >> 3;                   // lane row within 8-row/1KB chunk
    const int lc = (((ln & 7) ^ lr) * 8);     // swizzled global chunk (elements)
    const int sw = (l31 & 7);                 // frag-read swizzle key

    for (int k0 = 0; k0 < K; k0 += 64) {
        __syncthreads(); // prior iter's LDS reads done before overwrite
#pragma unroll
        for (int c = 0; c < 4; c++) {
            int rowA = wv * 32 + c * 8;
            const unsigned short* gA = A + (size_t)(m0 + rowA + lr) * K + k0 + lc;
            __builtin_amdgcn_global_load_lds(
                (const __attribute__((address_space(1))) void*)gA,
                (__attribute__((address_space(3))) void*)&At[rowA * 64], 16, 0, 0);
            const unsigned short* gB = W + (size_t)(n0 + rowA + lr) * K + k0 + lc;
            __builtin_amdgcn_global_load_lds(
                (const __attribute__((address_space(1))) void*)gB,
                (__attribute__((address_space(3))) void*)&Bt[rowA * 64], 16, 0, 0);
        }
        __syncthreads(); // drains vmcnt (compiler emits waitcnt before barrier)

#pragma unroll
        for (int ks = 0; ks < 4; ks++) {
            const int slot = ((ks * 2 + half) ^ sw) * 8;
            short8 af[2], bf[2];
#pragma unroll
            for (int mt = 0; mt < 2; mt++)
                af[mt] = *(const short8*)&At[(wm + mt * 32 + l31) * 64 + slot];
#pragma unroll
            for (int nt = 0; nt < 2; nt++)
                bf[nt] = *(const short8*)&Bt[(wn + nt * 32 + l31) * 64 + slot];
#pragma unroll
            for (int mt = 0; mt < 2; mt++)
#pragma unroll
                for (int nt = 0; nt < 2; nt++)
                    acc[mt][nt] = __builtin_amdgcn_mfma_f32_32x32x16_bf16(af[mt], bf[nt], acc[mt][nt], 0, 0, 0);
        }
    }

    // D layout (32x32): col = l31 (from B/n), row = (e&3) + 8*(e>>2) + 4*half
    const float esc = (VT2 && blockIdx.z == 0) ? QSCL : 1.0f; // fold softmax scale into Q

    if constexpr (VT2) {
        if (blockIdx.z == 2) {
            // transposed V store: Vt[(b*1024 + col)*2048 + s]; reg quad = 4 consec s
            unsigned short* Vt = (unsigned short*)C;
#pragma unroll
            for (int mt = 0; mt < 2; mt++)
#pragma unroll
                for (int nt = 0; nt < 2; nt++)
#pragma unroll
                    for (int rg = 0; rg < 4; rg++) {
                        int col = n0 + wn + nt * 32 + l31;
                        int row0 = m0 + wm + mt * 32 + 4 * half + 8 * rg; // %4==0
                        int bb = row0 >> 11, ss = row0 & 2047;
                        size_t addr = ((size_t)(bb * 1024 + col)) * 2048 + ss;
                        uint2 pk;
                        pk.x = pack2bf(acc[mt][nt][4 * rg + 0], acc[mt][nt][4 * rg + 1]);
                        pk.y = pack2bf(acc[mt][nt][4 * rg + 2], acc[mt][nt][4 * rg + 3]);
                        *(uint2*)(Vt + addr) = pk;
                    }
            return;
        }
    }

#pragma unroll
    for (int mt = 0; mt < 2; mt++)
#pragma unroll
        for (int nt = 0; nt < 2; nt++)
#pragma unroll
            for (int rg = 0; rg < 4; rg++)
#pragma unroll
                for (int r = 0; r < 4; r++) {
                    int row = m0 + wm + mt * 32 + 4 * half + 8 * rg + r;
                    int col = n0 + wn + nt * 32 + l31;
                    float v = acc[mt][nt][4 * rg + r] * esc;
                    if constexpr (sizeof(OutT) == 2)
                        C[(size_t)row * N + col] = (OutT)f2bf(v);
                    else
                        C[(size_t)row * N + col] = v;
                }
}

// ---------------- flash attention (v14: 4-wave blocks, qt=16, phase-diverse) ----------------
// Q (pre-scaled by QSCL), K, O: [B*S, D] bf16; Vt: [B*H*DK, S] bf16.
// v14 vs v9: same 16 waves/CU, but from FOUR independent 4-wave blocks (qt=16,
// 128 q/block) instead of two 8-wave lockstep blocks. Each block's barrier syncs
// only 4 waves; 4 blocks/CU at independent phases interleave MFMA-phase and
// VALU-phase waves on every SIMD. LDS 36 KB x 4 blocks = 144 <= 160 KB.
// Inner loop byte-identical to proven v9. Staging: v6's 4-chunk pattern
// (256 thr cover 64 rows of K and V). Grid (pair, qt): id%8 = pair%8 -> XCD
// colocation of all 16 qt-blocks sharing one (b,h)'s K/V.
__global__ __launch_bounds__(256, 4) void flash_attn(
    const unsigned short* __restrict__ Q,
    const unsigned short* __restrict__ K,
    const unsigned short* __restrict__ Vt,
    unsigned short* __restrict__ O)
{
    __shared__ __align__(16) unsigned short Kt[2][64 * 72]; // [buf][key][dk], +8 pad
    __shared__ __align__(16) unsigned short VT[2][64 * 72]; // [buf][dk][key], +8 pad

    const int pair = blockIdx.x; // 0..63: (b,h)
    const int h = pair & 15;
    const int b = pair >> 4;
    const int qt = blockIdx.y;   // 0..15
    const int tid = threadIdx.x; // 0..255
    const int wv = tid >> 6;     // 0..3
    const int ln = tid & 63;
    const int l31 = ln & 31;
    const int half = ln >> 5;

    const size_t base = ((size_t)b * S_) * D_ + (size_t)h * DK_; // Q,K,O
    const size_t vtbase = ((size_t)(b * 1024 + h * 64)) * (size_t)S_;

    // Q B-fragment: lane l31 = q-row of this wave's 32-q slice, k-contig
    const int qrow = qt * 128 + wv * 32 + l31;
    short8 qf[4];
    {
        const unsigned short* qp = Q + base + (size_t)qrow * D_ + half * 8;
#pragma unroll
        for (int ks = 0; ks < 4; ks++) qf[ks] = *(const short8*)(qp + ks * 16);
    }

    floatx16 Oacc[2]; // [mt]
#pragma unroll
    for (int mt = 0; mt < 2; mt++)
#pragma unroll
        for (int e = 0; e < 16; e++) Oacc[mt][e] = 0.f;
    float l_i = 0.f;

    // staging: 256 threads, 8 lanes/row -> 32 rows; each thread stages 2 K-chunks
    // + 2 V-chunks per tile (coalesced 128B rows); pointers increment
    const int srow = tid >> 3;      // 0..31
    const int scol = (tid & 7) * 8; // col chunk
    const unsigned short* kp0 = K + base + (size_t)srow * D_ + scol;
    const unsigned short* kp1 = kp0 + (size_t)32 * D_;
    const unsigned short* vp0 = Vt + vtbase + (size_t)srow * S_ + scol;
    const unsigned short* vp1 = vp0 + (size_t)32 * S_;
    const int swo = srow * 72 + scol; // LDS write offset (elements)

    // prologue: stage tile 0 into registers
    short8 kr0 = *(const short8*)kp0;
    short8 kr1 = *(const short8*)kp1;
    short8 vr0 = *(const short8*)vp0;
    short8 vr1 = *(const short8*)vp1;
    kp0 += (size_t)64 * D_; kp1 += (size_t)64 * D_;
    vp0 += 64; vp1 += 64;

    for (int kt = 0; kt < S_ / 64; kt++) {
        const int cb = kt & 1;
        unsigned short* Kc = &Kt[cb][0];
        unsigned short* Vc = &VT[cb][0];
        // write staged regs into current buffer. Safe: all reads of this buffer
        // (iter kt-2's compute) finished before every thread reached barrier kt-1.
        *(short8*)&Kc[swo] = kr0;
        *(short8*)&Kc[swo + 32 * 72] = kr1;
        *(short8*)&Vc[swo] = vr0;
        *(short8*)&Vc[swo + 32 * 72] = vr1;
        __syncthreads(); // single barrier per iter (4 waves only)

        // prefetch tile kt+1: issues now, lands during compute below
        if (kt < S_ / 64 - 1) {
            kr0 = *(const short8*)kp0;
            kr1 = *(const short8*)kp1;
            vr0 = *(const short8*)vp0;
            vr1 = *(const short8*)vp1;
            kp0 += (size_t)64 * D_; kp1 += (size_t)64 * D_;
            vp0 += 64; vp1 += 64;
        }

        uint2 run[2][4]; // [mt][g], keys mt*32 + 8g + 4*half + {0..3}

        // S^T = K Q^T per mt (32 keys x 32 q)
#pragma unroll
        for (int mt = 0; mt < 2; mt++) {
            floatx16 sac;
#pragma unroll
            for (int e = 0; e < 16; e++) sac[e] = 0.f;
            __builtin_amdgcn_s_setprio(1);
#pragma unroll
            for (int ks = 0; ks < 4; ks++) {
                short8 kf = *(const short8*)&Kc[(mt * 32 + l31) * 72 + ks * 16 + half * 8];
                sac = __builtin_amdgcn_mfma_f32_32x32x16_bf16(kf, qf[ks], sac, 0, 0, 0);
            }
            __builtin_amdgcn_s_setprio(0);
            // p = exp2(s); accumulate per-lane l partials; pack to bf16 pairs
#pragma unroll
            for (int g = 0; g < 4; g++) {
                float p0 = __builtin_amdgcn_exp2f(sac[4 * g + 0]);
                float p1 = __builtin_amdgcn_exp2f(sac[4 * g + 1]);
                float p2 = __builtin_amdgcn_exp2f(sac[4 * g + 2]);
                float p3 = __builtin_amdgcn_exp2f(sac[4 * g + 3]);
                l_i += (p0 + p1) + (p2 + p3);
                run[mt][g].x = pack2bf_perm(p0, p1);
                run[mt][g].y = pack2bf_perm(p2, p3);
            }
        }

        // rearrange runs into B-fragments (swap hi-lanes of even-g with lo-lanes of odd-g)
#pragma unroll
        for (int mt = 0; mt < 2; mt++)
#pragma unroll
            for (int t = 0; t < 2; t++) {
                PLSWAP(run[mt][2 * t].x, run[mt][2 * t + 1].x);
                PLSWAP(run[mt][2 * t].y, run[mt][2 * t + 1].y);
            }

        // O^T = V^T P^T
#pragma unroll
        for (int mt2 = 0; mt2 < 2; mt2++)
#pragma unroll
            for (int t = 0; t < 2; t++) {
                int ks = mt2 * 2 + t;
                uint4v u = {run[mt2][2 * t].x, run[mt2][2 * t].y,
                            run[mt2][2 * t + 1].x, run[mt2][2 * t + 1].y};
                short8 pf = __builtin_bit_cast(short8, u);
                __builtin_amdgcn_s_setprio(1);
#pragma unroll
                for (int mt = 0; mt < 2; mt++) {
                    short8 vf = *(const short8*)&Vc[(mt * 32 + l31) * 72 + ks * 16 + half * 8];
                    Oacc[mt] = __builtin_amdgcn_mfma_f32_32x32x16_bf16(vf, pf, Oacc[mt], 0, 0, 0);
                }
                __builtin_amdgcn_s_setprio(0);
            }
    }

    // epilogue: lanes (l, l+32) hold complementary key partials for the same q
    {
        float ls = l_i + __shfl_xor(l_i, 32);
        float inv = 1.0f / ls;
        const size_t orow = base + (size_t)qrow * D_;
#pragma unroll
        for (int mt = 0; mt < 2; mt++)
#pragma unroll
            for (int g = 0; g < 4; g++) {
                uint2 pk;
                pk.x = pack2bf(Oacc[mt][4 * g + 0] * inv, Oacc[mt][4 * g + 1] * inv);
                pk.y = pack2bf(Oacc[mt][4 * g + 2] * inv, Oacc[mt][4 * g + 3] * inv);
                *(uint2*)(O + orow + mt * 32 + 8 * g + 4 * half) = pk;
            }
    }
}

extern "C" void kernel_launch(void* const* d_in, const int* in_sizes, int n_in,
                              void* d_out, int out_size, void* d_ws, size_t ws_size,
                              hipStream_t stream) {
    const float* x  = (const float*)d_in[0];
    const float* Wq = (const float*)d_in[1];
    const float* Wk = (const float*)d_in[2];
    const float* Wv = (const float*)d_in[3];
    const float* Wo = (const float*)d_in[4];
    float* out = (float*)d_out;

    char* ws = (char*)d_ws;
    const size_t MB = 1024 * 1024;
    unsigned short* xb  = (unsigned short*)(ws);            // 16 MB
    unsigned short* wqb = (unsigned short*)(ws + 16 * MB);  // 2 MB each
    unsigned short* wkb = (unsigned short*)(ws + 18 * MB);
    unsigned short* wvb = (unsigned short*)(ws + 20 * MB);
    unsigned short* wob = (unsigned short*)(ws + 22 * MB);
    unsigned short* Qb  = (unsigned short*)(ws + 24 * MB);  // 16 MB
    unsigned short* Kb  = (unsigned short*)(ws + 40 * MB);
    unsigned short* Vtb = (unsigned short*)(ws + 56 * MB);  // V transposed [B*H*DK, S]
    unsigned short* Ob  = (unsigned short*)(ws);            // alias xb (dead after QKV GEMM)

    CastAll ca;
    ca.x = x; ca.xd = xb;
    ca.w[0] = Wq; ca.w[1] = Wk; ca.w[2] = Wv; ca.w[3] = Wo;
    ca.wd[0] = wqb; ca.wd[1] = wkb; ca.wd[2] = wvb; ca.wd[3] = wob;
    cast_all_kernel<<<12288, 256, 0, stream>>>(ca);

    // grid (m-tile, n-tile, z): id%8 = m-tile%8 -> XCD locality on A (proven v10)
    dim3 gq((B_ * S_) / 128, D_ / 128, 3); // (64, 8, 3)
    gemm_bt<unsigned short, true><<<gq, 256, 0, stream>>>(
        xb, wqb, wkb, wvb, Qb, Kb, Vtb, B_ * S_, D_, D_);

    // grid (pair, qt): id%8 = pair%8 -> XCD colocation; 1024 blocks x 4 waves
    dim3 gf(64, S_ / 128, 1); // (64, 16)
    flash_attn<<<gf, 256, 0, stream>>>(Qb, Kb, Vtb, Ob);

    dim3 go((B_ * S_) / 128, D_ / 128, 1); // (64, 8)
    gemm_bt<float, false><<<go, 256, 0, stream>>>(
        Ob, wob, wob, wob, out, out, out, B_ * S_, D_, D_);
}

// Round 9
// 264.725 us; speedup vs baseline: 1.0665x; 1.0665x over previous
//
#include <hip/hip_runtime.h>
#include <hip/hip_bf16.h>

// Problem constants (fixed by reference)
#define B_ 4
#define S_ 2048
#define D_ 1024
#define H_ 16
#define DK_ 64

typedef __attribute__((ext_vector_type(8))) short short8;
typedef __attribute__((ext_vector_type(4))) float floatx4;
typedef __attribute__((ext_vector_type(16))) float floatx16;
typedef __attribute__((ext_vector_type(4))) unsigned int uint4v;

#define QSCL 0.1803368801111204f  // log2(e)/sqrt(DK): folded into Q in GEMM epilogue

// round-to-nearest-even f32 -> bf16 bits
static __device__ __forceinline__ unsigned short f2bf(float f) {
    unsigned int u = __float_as_uint(f);
    u += 0x7fffu + ((u >> 16) & 1u);
    return (unsigned short)(u >> 16);
}

// pack two f32 -> bf16x2, round-nearest-ties-up via v_perm_b32 (3 VALU ops) [proven]
static __device__ __forceinline__ unsigned int pack2bf_perm(float a, float b) {
    unsigned int u0 = __float_as_uint(a) + 0x8000u;
    unsigned int u1 = __float_as_uint(b) + 0x8000u;
    return __builtin_amdgcn_perm(u1, u0, 0x07060302u);
}

// pack two f32 -> bf16x2 (RNE, for outputs) [proven]
static __device__ __forceinline__ unsigned int pack2bf(float a, float b) {
    return (unsigned int)f2bf(a) | ((unsigned int)f2bf(b) << 16);
}

// v_permlane32_swap_b32 a, b : lanes[32:63] of a  <->  lanes[0:31] of b
#define PLSWAP(a, b) asm volatile("v_permlane32_swap_b32 %0, %1" : "+v"(a), "+v"(b))

// ---------------- fused cast kernel (x + 4 weights in one launch) ----------------
struct CastAll {
    const float* x;
    const float* w[4];
    unsigned short* xd;
    unsigned short* wd[4];
};

__global__ void cast_all_kernel(CastAll a) {
    int i = blockIdx.x * blockDim.x + threadIdx.x; // over float4 groups
    const float* s;
    unsigned short* d;
    int j;
    if (i < 2097152) { // x: 8M elems = 2M float4
        s = a.x; d = a.xd; j = i;
    } else {           // 4 weights: 256K float4 each
        int k = i - 2097152;
        int w = k >> 18;
        j = k & 262143;
        s = a.w[w]; d = a.wd[w];
    }
    float4 v = ((const float4*)s)[j];
    ushort4 o;
    o.x = f2bf(v.x); o.y = f2bf(v.y); o.z = f2bf(v.z); o.w = f2bf(v.w);
    ((ushort4*)d)[j] = o;
}

// ---------------- GEMM (v10, proven best: 128x128, 2-barrier, multi-block/CU) ----------------
// C[m,n] = sum_k A[m,k] * W[n,k]. A: [M,K] bf16; W: [N,K] bf16 (torch [out,in]).
// 128x128 tile, BK=64, 256 threads, global_load_lds width=16.
// LDS swizzle: chunk c (16B) of row r stored at slot c ^ (r&7); staging lane ln
// loads global chunk (ln&7)^(lr) -> coalesced; frag reads conflict-free.
// Grid (m-tile, n-tile, z): id%8 = m-tile%8 -> XCD L2 locality on A.
// Session evidence: 256^2 early-issue dbuf (R5) and 256x128 triple-buffer
// counted-vmcnt (R6) both regressed vs this at <=1 block/CU; the implicit
// 3-4 blocks/CU overlap of this structure is what delivers its throughput.
// VT2 (QKV launch): z==0 (Q) epilogue pre-scales by QSCL; z==2 (V) stores
// transposed Vt[(b*1024+col)][s].
template <typename OutT, bool VT2>
__global__ __launch_bounds__(256) void gemm_bt(
    const unsigned short* __restrict__ A,
    const unsigned short* __restrict__ W0,
    const unsigned short* __restrict__ W1,
    const unsigned short* __restrict__ W2,
    OutT* __restrict__ C0, OutT* __restrict__ C1, OutT* __restrict__ C2,
    int M, int N, int K)
{
    __shared__ __align__(16) unsigned short At[128 * 64]; // [row][slot^swizzle], NO pad
    __shared__ __align__(16) unsigned short Bt[128 * 64];

    const unsigned short* W = (blockIdx.z == 0) ? W0 : ((blockIdx.z == 1) ? W1 : W2);
    OutT* C = (blockIdx.z == 0) ? C0 : ((blockIdx.z == 1) ? C1 : C2);

    const int m0 = blockIdx.x * 128;  // m-tile fastest: id%8 = m-tile%8 -> XCD locality
    const int n0 = blockIdx.y * 128;
    const int wv = threadIdx.x >> 6;
    const int ln = threadIdx.x & 63;
    const int l31 = ln & 31;
    const int half = ln >> 5;
    const int wm = (wv >> 1) * 64; // wave's 64x64 quadrant
    const int wn = (wv & 1) * 64;

    floatx16 acc[2][2]; // [mt][nt] 32x32 tiles
#pragma unroll
    for (int mt = 0; mt < 2; mt++)
#pragma unroll
        for (int nt = 0; nt < 2; nt++)
#pragma unroll
            for (int e = 0; e < 16; e++) acc[mt][nt][e] = 0.f;

    const int lr = ln >> 3;                   // lane row within 8-row/1KB chunk
    const int lc = (((ln & 7) ^ lr) * 8);     // swizzled global chunk (elements)
    const int sw = (l31 & 7);                 // frag-read swizzle key

    for (int k0 = 0; k0 < K; k0 += 64) {
        __syncthreads(); // prior iter's LDS reads done before overwrite
#pragma unroll
        for (int c = 0; c < 4; c++) {
            int rowA = wv * 32 + c * 8;
            const unsigned short* gA = A + (size_t)(m0 + rowA + lr) * K + k0 + lc;
            __builtin_amdgcn_global_load_lds(
                (const __attribute__((address_space(1))) void*)gA,
                (__attribute__((address_space(3))) void*)&At[rowA * 64], 16, 0, 0);
            const unsigned short* gB = W + (size_t)(n0 + rowA + lr) * K + k0 + lc;
            __builtin_amdgcn_global_load_lds(
                (const __attribute__((address_space(1))) void*)gB,
                (__attribute__((address_space(3))) void*)&Bt[rowA * 64], 16, 0, 0);
        }
        __syncthreads(); // drains vmcnt (compiler emits waitcnt before barrier)

#pragma unroll
        for (int ks = 0; ks < 4; ks++) {
            const int slot = ((ks * 2 + half) ^ sw) * 8;
            short8 af[2], bf[2];
#pragma unroll
            for (int mt = 0; mt < 2; mt++)
                af[mt] = *(const short8*)&At[(wm + mt * 32 + l31) * 64 + slot];
#pragma unroll
            for (int nt = 0; nt < 2; nt++)
                bf[nt] = *(const short8*)&Bt[(wn + nt * 32 + l31) * 64 + slot];
#pragma unroll
            for (int mt = 0; mt < 2; mt++)
#pragma unroll
                for (int nt = 0; nt < 2; nt++)
                    acc[mt][nt] = __builtin_amdgcn_mfma_f32_32x32x16_bf16(af[mt], bf[nt], acc[mt][nt], 0, 0, 0);
        }
    }

    // D layout (32x32): col = l31 (from B/n), row = (e&3) + 8*(e>>2) + 4*half
    const float esc = (VT2 && blockIdx.z == 0) ? QSCL : 1.0f; // fold softmax scale into Q

    if constexpr (VT2) {
        if (blockIdx.z == 2) {
            // transposed V store: Vt[(b*1024 + col)*2048 + s]; reg quad = 4 consec s
            unsigned short* Vt = (unsigned short*)C;
#pragma unroll
            for (int mt = 0; mt < 2; mt++)
#pragma unroll
                for (int nt = 0; nt < 2; nt++)
#pragma unroll
                    for (int rg = 0; rg < 4; rg++) {
                        int col = n0 + wn + nt * 32 + l31;
                        int row0 = m0 + wm + mt * 32 + 4 * half + 8 * rg; // %4==0
                        int bb = row0 >> 11, ss = row0 & 2047;
                        size_t addr = ((size_t)(bb * 1024 + col)) * 2048 + ss;
                        uint2 pk;
                        pk.x = pack2bf(acc[mt][nt][4 * rg + 0], acc[mt][nt][4 * rg + 1]);
                        pk.y = pack2bf(acc[mt][nt][4 * rg + 2], acc[mt][nt][4 * rg + 3]);
                        *(uint2*)(Vt + addr) = pk;
                    }
            return;
        }
    }

#pragma unroll
    for (int mt = 0; mt < 2; mt++)
#pragma unroll
        for (int nt = 0; nt < 2; nt++)
#pragma unroll
            for (int rg = 0; rg < 4; rg++)
#pragma unroll
                for (int r = 0; r < 4; r++) {
                    int row = m0 + wm + mt * 32 + 4 * half + 8 * rg + r;
                    int col = n0 + wn + nt * 32 + l31;
                    float v = acc[mt][nt][4 * rg + r] * esc;
                    if constexpr (sizeof(OutT) == 2)
                        C[(size_t)row * N + col] = (OutT)f2bf(v);
                    else
                        C[(size_t)row * N + col] = v;
                }
}

// ---------------- flash attention (v9, proven best: 32 q/wave, 8 waves, XCD-colocated) ----------------
// Q (pre-scaled by QSCL), K, O: [B*S, D] bf16; Vt: [B*H*DK, S] bf16.
// Plateau evidence (R7/R8): split-K 16-wave blocks (92us) and 4-wave blocks
// (91us) both regressed vs this (87us). At 87us the three pipes are balanced:
// MFMA ~29us busy (27.5us is the 2.5PF floor for 68.7GF — near work-optimal),
// DS ~40us (2.1GB LDS reads), VALU ~43us (exp/pack chain); serialized by the
// per-iter QK->exp->pack->PV dependency. Next step would be the HK 4-cluster
// co-design (T16), which does not graft piecemeal.
__global__ __launch_bounds__(512, 4) void flash_attn(
    const unsigned short* __restrict__ Q,
    const unsigned short* __restrict__ K,
    const unsigned short* __restrict__ Vt,
    unsigned short* __restrict__ O)
{
    __shared__ __align__(16) unsigned short Kt[2][64 * 72]; // [buf][key][dk], +8 pad
    __shared__ __align__(16) unsigned short VT[2][64 * 72]; // [buf][dk][key], +8 pad

    const int pair = blockIdx.x; // 0..63: (b,h)
    const int h = pair & 15;
    const int b = pair >> 4;
    const int qt = blockIdx.y;   // 0..7
    const int tid = threadIdx.x;
    const int wv = tid >> 6;     // 0..7
    const int ln = tid & 63;
    const int l31 = ln & 31;
    const int half = ln >> 5;

    const size_t base = ((size_t)b * S_) * D_ + (size_t)h * DK_; // Q,K,O
    const size_t vtbase = ((size_t)(b * 1024 + h * 64)) * (size_t)S_;

    // Q B-fragment: lane l31 = q-row of this wave's 32-q slice, k-contig
    const int qrow = qt * 256 + wv * 32 + l31;
    short8 qf[4];
    {
        const unsigned short* qp = Q + base + (size_t)qrow * D_ + half * 8;
#pragma unroll
        for (int ks = 0; ks < 4; ks++) qf[ks] = *(const short8*)(qp + ks * 16);
    }

    floatx16 Oacc[2]; // [mt]
#pragma unroll
    for (int mt = 0; mt < 2; mt++)
#pragma unroll
        for (int e = 0; e < 16; e++) Oacc[mt][e] = 0.f;
    float l_i = 0.f;

    // staging: 512 threads, 8 lanes cover one 64-elem row (coalesced 128B);
    // each thread stages exactly one K chunk + one V chunk per tile.
    const int srow = tid >> 3;      // 0..63
    const int scol = (tid & 7) * 8; // col chunk
    const unsigned short* kp = K + base + (size_t)srow * D_ + scol;
    const unsigned short* vp = Vt + vtbase + (size_t)srow * S_ + scol;
    const int swo = srow * 72 + scol; // LDS write offset (elements)

    // prologue: stage tile 0 into registers
    short8 kr = *(const short8*)kp;
    short8 vr = *(const short8*)vp;
    kp += (size_t)64 * D_;
    vp += 64;

    for (int kt = 0; kt < S_ / 64; kt++) {
        const int cb = kt & 1;
        unsigned short* Kc = &Kt[cb][0];
        unsigned short* Vc = &VT[cb][0];
        // write staged regs into current buffer. Safe: all reads of this buffer
        // (iter kt-2's compute) finished before every thread reached barrier kt-1.
        *(short8*)&Kc[swo] = kr;
        *(short8*)&Vc[swo] = vr;
        __syncthreads(); // single barrier per iter: writes visible, prev-buf reads done

        // prefetch tile kt+1: issues now, lands during compute below
        if (kt < S_ / 64 - 1) {
            kr = *(const short8*)kp;
            vr = *(const short8*)vp;
            kp += (size_t)64 * D_;
            vp += 64;
        }

        uint2 run[2][4]; // [mt][g], keys mt*32 + 8g + 4*half + {0..3}

        // S^T = K Q^T per mt (32 keys x 32 q)
#pragma unroll
        for (int mt = 0; mt < 2; mt++) {
            floatx16 sac;
#pragma unroll
            for (int e = 0; e < 16; e++) sac[e] = 0.f;
            __builtin_amdgcn_s_setprio(1);
#pragma unroll
            for (int ks = 0; ks < 4; ks++) {
                short8 kf = *(const short8*)&Kc[(mt * 32 + l31) * 72 + ks * 16 + half * 8];
                sac = __builtin_amdgcn_mfma_f32_32x32x16_bf16(kf, qf[ks], sac, 0, 0, 0);
            }
            __builtin_amdgcn_s_setprio(0);
            // p = exp2(s); accumulate per-lane l partials; pack to bf16 pairs
#pragma unroll
            for (int g = 0; g < 4; g++) {
                float p0 = __builtin_amdgcn_exp2f(sac[4 * g + 0]);
                float p1 = __builtin_amdgcn_exp2f(sac[4 * g + 1]);
                float p2 = __builtin_amdgcn_exp2f(sac[4 * g + 2]);
                float p3 = __builtin_amdgcn_exp2f(sac[4 * g + 3]);
                l_i += (p0 + p1) + (p2 + p3);
                run[mt][g].x = pack2bf_perm(p0, p1);
                run[mt][g].y = pack2bf_perm(p2, p3);
            }
        }

        // rearrange runs into B-fragments (swap hi-lanes of even-g with lo-lanes of odd-g)
#pragma unroll
        for (int mt = 0; mt < 2; mt++)
#pragma unroll
            for (int t = 0; t < 2; t++) {
                PLSWAP(run[mt][2 * t].x, run[mt][2 * t + 1].x);
                PLSWAP(run[mt][2 * t].y, run[mt][2 * t + 1].y);
            }

        // O^T = V^T P^T
#pragma unroll
        for (int mt2 = 0; mt2 < 2; mt2++)
#pragma unroll
            for (int t = 0; t < 2; t++) {
                int ks = mt2 * 2 + t;
                uint4v u = {run[mt2][2 * t].x, run[mt2][2 * t].y,
                            run[mt2][2 * t + 1].x, run[mt2][2 * t + 1].y};
                short8 pf = __builtin_bit_cast(short8, u);
                __builtin_amdgcn_s_setprio(1);
#pragma unroll
                for (int mt = 0; mt < 2; mt++) {
                    short8 vf = *(const short8*)&Vc[(mt * 32 + l31) * 72 + ks * 16 + half * 8];
                    Oacc[mt] = __builtin_amdgcn_mfma_f32_32x32x16_bf16(vf, pf, Oacc[mt], 0, 0, 0);
                }
                __builtin_amdgcn_s_setprio(0);
            }
    }

    // epilogue: lanes (l, l+32) hold complementary key partials for the same q
    {
        float ls = l_i + __shfl_xor(l_i, 32);
        float inv = 1.0f / ls;
        const size_t orow = base + (size_t)qrow * D_;
#pragma unroll
        for (int mt = 0; mt < 2; mt++)
#pragma unroll
            for (int g = 0; g < 4; g++) {
                uint2 pk;
                pk.x = pack2bf(Oacc[mt][4 * g + 0] * inv, Oacc[mt][4 * g + 1] * inv);
                pk.y = pack2bf(Oacc[mt][4 * g + 2] * inv, Oacc[mt][4 * g + 3] * inv);
                *(uint2*)(O + orow + mt * 32 + 8 * g + 4 * half) = pk;
            }
    }
}

extern "C" void kernel_launch(void* const* d_in, const int* in_sizes, int n_in,
                              void* d_out, int out_size, void* d_ws, size_t ws_size,
                              hipStream_t stream) {
    const float* x  = (const float*)d_in[0];
    const float* Wq = (const float*)d_in[1];
    const float* Wk = (const float*)d_in[2];
    const float* Wv = (const float*)d_in[3];
    const float* Wo = (const float*)d_in[4];
    float* out = (float*)d_out;

    char* ws = (char*)d_ws;
    const size_t MB = 1024 * 1024;
    unsigned short* xb  = (unsigned short*)(ws);            // 16 MB
    unsigned short* wqb = (unsigned short*)(ws + 16 * MB);  // 2 MB each
    unsigned short* wkb = (unsigned short*)(ws + 18 * MB);
    unsigned short* wvb = (unsigned short*)(ws + 20 * MB);
    unsigned short* wob = (unsigned short*)(ws + 22 * MB);
    unsigned short* Qb  = (unsigned short*)(ws + 24 * MB);  // 16 MB
    unsigned short* Kb  = (unsigned short*)(ws + 40 * MB);
    unsigned short* Vtb = (unsigned short*)(ws + 56 * MB);  // V transposed [B*H*DK, S]
    unsigned short* Ob  = (unsigned short*)(ws);            // alias xb (dead after QKV GEMM)

    CastAll ca;
    ca.x = x; ca.xd = xb;
    ca.w[0] = Wq; ca.w[1] = Wk; ca.w[2] = Wv; ca.w[3] = Wo;
    ca.wd[0] = wqb; ca.wd[1] = wkb; ca.wd[2] = wvb; ca.wd[3] = wob;
    cast_all_kernel<<<12288, 256, 0, stream>>>(ca);

    // grid (m-tile, n-tile, z): id%8 = m-tile%8 -> XCD locality on A (proven v10)
    dim3 gq((B_ * S_) / 128, D_ / 128, 3); // (64, 8, 3)
    gemm_bt<unsigned short, true><<<gq, 256, 0, stream>>>(
        xb, wqb, wkb, wvb, Qb, Kb, Vtb, B_ * S_, D_, D_);

    // grid (pair, qt): id%8 = pair%8 -> all qt-blocks of one (b,h) share an XCD
    dim3 gf(64, S_ / 256, 1); // (64, 8) = 512 blocks x 512 thr
    flash_attn<<<gf, 512, 0, stream>>>(Qb, Kb, Vtb, Ob);

    dim3 go((B_ * S_) / 128, D_ / 128, 1); // (64, 8)
    gemm_bt<float, false><<<go, 256, 0, stream>>>(
        Ob, wob, wob, wob, out, out, out, B_ * S_, D_, D_);
}